// Round 2
// baseline (3906.033 us; speedup 1.0000x reference)
//
#include <hip/hip_runtime.h>
#include <math.h>

#define NTH 256

__device__ __forceinline__ unsigned enc_f(float x){
  unsigned u = __float_as_uint(x);
  return (u & 0x80000000u) ? ~u : (u | 0x80000000u);
}
__device__ __forceinline__ float dec_f(unsigned v){
  unsigned u = (v & 0x80000000u) ? (v & 0x7FFFFFFFu) : ~v;
  return __uint_as_float(u);
}

// ---------------------------------------------------------------------------
// Node linear: out[N,DO] = x[N,DI] @ W[DI,DO] (+ bias). JSPLIT waves per row
// group; W reads wave-uniform s_loads. (unchanged from round 1)
// ---------------------------------------------------------------------------
template<int DI, int DIS, int DO, int DOS, int JSPLIT, int MINW>
__global__ __launch_bounds__(NTH, MINW) void node_linear_k(
    const float* __restrict__ x, const float* __restrict__ W,
    const float* __restrict__ bias, float* __restrict__ out, int N)
{
  constexpr int WPB = NTH / 64;
  constexpr int GPB = WPB / JSPLIT;
  constexpr int DOW = DO / JSPLIT;
  const int lane = threadIdx.x & 63;
  const int wave = threadIdx.x >> 6;
  const int group = blockIdx.x * GPB + (wave / JSPLIT);
  const int j0 = __builtin_amdgcn_readfirstlane((wave % JSPLIT) * DOW);
  const int row = group * 64 + lane;
  const bool valid = row < N;
  const int rr = valid ? row : (N - 1);
  const float* xr = x + (size_t)rr * DIS;

  float acc[DOW];
  if (bias != nullptr) {
    #pragma unroll
    for (int j = 0; j < DOW; j++) acc[j] = bias[j0 + j];
  } else {
    #pragma unroll
    for (int j = 0; j < DOW; j++) acc[j] = 0.f;
  }

  constexpr int K4 = DI & ~3;
  for (int k = 0; k < K4; k += 4) {
    float4 ev = *(const float4*)(xr + k);
    float ea[4] = {ev.x, ev.y, ev.z, ev.w};
    #pragma unroll
    for (int kk = 0; kk < 4; kk++) {
      const float* wr = W + (size_t)(k + kk) * DO + j0;
      #pragma unroll
      for (int j = 0; j < DOW; j++)
        acc[j] = fmaf(ea[kk], wr[j], acc[j]);
    }
  }
  #pragma unroll
  for (int k = K4; k < DI; k++) {
    float ev = xr[k];
    const float* wr = W + (size_t)k * DO + j0;
    #pragma unroll
    for (int j = 0; j < DOW; j++)
      acc[j] = fmaf(ev, wr[j], acc[j]);
  }

  if (valid) {
    float* orow = out + (size_t)row * DOS + j0;
    constexpr int J4 = DOW & ~3;
    #pragma unroll
    for (int j = 0; j < J4; j += 4)
      *(float4*)(orow + j) = make_float4(acc[j], acc[j+1], acc[j+2], acc[j+3]);
    #pragma unroll
    for (int j = J4; j < DOW; j++) orow[j] = acc[j];
  }
}

// ---------------------------------------------------------------------------
// STAGED edge kernel: one 64-edge group per block, 4 sub-waves each own
// DOW = DO/4 outputs (small acc -> high occupancy). The e-tile is loaded
// ONCE per group into XOR-swizzled LDS (no duplicated HBM stream), K-chunked
// (KC=32) with register prefetch of the next chunk overlapping compute.
// W/bias/attn stay wave-uniform s_loads. Score reduced across subs via LDS.
// ---------------------------------------------------------------------------
template<int DI, int DIS, int DOW, int DO, int DOS, bool SCORE, int MINW>
__global__ __launch_bounds__(NTH, MINW) void edge_f_s_k(
    const float* __restrict__ efeat, const float* __restrict__ xWni,
    const float* __restrict__ xWnj, const float* __restrict__ Wf,
    const float* __restrict__ attn, const float* __restrict__ bias,
    const int* __restrict__ src, const int* __restrict__ dst,
    float* __restrict__ fout, float* __restrict__ score,
    unsigned* __restrict__ menc, int E)
{
  constexpr int KC = 32;
  constexpr int NCH = (DI + KC - 1) / KC;
  constexpr bool KFULL = (DI % KC == 0);
  static_assert(KFULL || NCH == 1, "partial K chunk only supported as single chunk");
  static_assert(4 * DOW == DO, "4 sub-waves must tile DO exactly");
  constexpr int FPT = (64 * KC / 4) / NTH;   // float4 per thread per chunk (=2)

  const int tid  = threadIdx.x;
  const int lane = tid & 63;
  const int sub  = tid >> 6;
  const int j0 = __builtin_amdgcn_readfirstlane(sub * DOW);
  const int group = blockIdx.x;
  const int eidx = group * 64 + lane;
  const bool valid = eidx < E;
  const int ee = valid ? eidx : (E - 1);

  __shared__ float4 et[64 * 8];       // [row][8 f4], slot = row*8 + (c4^(row&7))
  __shared__ float scpart[4][64];

  // gather-init: acc = bias + xWni[src] + xWnj[dst] (each sub reads its j-slice)
  const int sn = src[ee];
  const int dn = dst[ee];
  const float* ar = xWni + (size_t)sn * DOS + j0;
  const float* br = xWnj + (size_t)dn * DOS + j0;

  float acc[DOW];
  #pragma unroll
  for (int j = 0; j < DOW; j += 4) {
    float4 a4 = *(const float4*)(ar + j);
    float4 b4 = *(const float4*)(br + j);
    acc[j+0] = bias[j0+j+0] + a4.x + b4.x;
    acc[j+1] = bias[j0+j+1] + a4.y + b4.y;
    acc[j+2] = bias[j0+j+2] + a4.z + b4.z;
    acc[j+3] = bias[j0+j+3] + a4.w + b4.w;
  }

  // prefetch chunk 0 into regs
  float4 pv[FPT];
  #pragma unroll
  for (int i = 0; i < FPT; i++) {
    int s = i * NTH + tid;
    int row = s >> 3, c4 = s & 7;
    int er = group * 64 + row; er = (er < E) ? er : (E - 1);
    pv[i] = *(const float4*)(efeat + (size_t)er * DIS + c4 * 4);
  }

  for (int ch = 0; ch < NCH; ++ch) {
    __syncthreads();                       // previous chunk's LDS reads done
    #pragma unroll
    for (int i = 0; i < FPT; i++) {
      int s = i * NTH + tid;
      int row = s >> 3, c4 = s & 7;
      et[row * 8 + (c4 ^ (row & 7))] = pv[i];
    }
    if (ch + 1 < NCH) {                    // prefetch next chunk (overlaps compute)
      #pragma unroll
      for (int i = 0; i < FPT; i++) {
        int s = i * NTH + tid;
        int row = s >> 3, c4 = s & 7;
        int er = group * 64 + row; er = (er < E) ? er : (E - 1);
        pv[i] = *(const float4*)(efeat + (size_t)er * DIS + (ch + 1) * KC + c4 * 4);
      }
    }
    __syncthreads();                       // tile visible

    #pragma unroll
    for (int c4 = 0; c4 < 8; ++c4) {
      if constexpr (!KFULL) { if (c4 * 4 >= DI) break; }
      float4 ev = et[lane * 8 + (c4 ^ (lane & 7))];
      float ea[4] = {ev.x, ev.y, ev.z, ev.w};
      #pragma unroll
      for (int kk = 0; kk < 4; kk++) {
        if constexpr (!KFULL) { if (c4 * 4 + kk >= DI) break; }
        const float* wr = Wf + (size_t)(ch * KC + c4 * 4 + kk) * DO + j0;
        #pragma unroll
        for (int j = 0; j < DOW; j++)
          acc[j] = fmaf(ea[kk], wr[j], acc[j]);
      }
    }
  }

  float sc = 0.f;
  #pragma unroll
  for (int j = 0; j < DOW; j++) {
    float v = acc[j];
    v = (v > 0.f) ? v : 0.01f * v;
    acc[j] = v;
    if (SCORE) sc += v * attn[j0 + j];
  }

  if (valid) {
    float* orow = fout + (size_t)eidx * DOS + j0;
    #pragma unroll
    for (int j = 0; j < DOW; j += 4)
      *(float4*)(orow + j) = make_float4(acc[j], acc[j+1], acc[j+2], acc[j+3]);
  }

  if constexpr (SCORE) {
    scpart[sub][lane] = sc;
    __syncthreads();
    if (sub == 0 && valid) {
      float tot = scpart[0][lane] + scpart[1][lane] + scpart[2][lane] + scpart[3][lane];
      score[eidx] = tot;
      atomicMax(&menc[dn], enc_f(tot));
    }
  }
}

// ---------------------------------------------------------------------------
// Edge kernel (direct per-lane stream) — used for layer 2 (DO=30, JSPLIT=1).
// ---------------------------------------------------------------------------
template<int DI, int DIS, int DO, int DOS, bool SCORE, int MINW>
__global__ __launch_bounds__(NTH, MINW) void edge_f_k(
    const float* __restrict__ efeat, const float* __restrict__ xWni,
    const float* __restrict__ xWnj, const float* __restrict__ Wf,
    const float* __restrict__ attn, const float* __restrict__ bias,
    const int* __restrict__ src, const int* __restrict__ dst,
    float* __restrict__ fout, float* __restrict__ score,
    unsigned* __restrict__ menc, int E)
{
  const int lane = threadIdx.x & 63;
  const int wave = threadIdx.x >> 6;
  const int eidx = (blockIdx.x * (NTH >> 6) + wave) * 64 + lane;
  const bool valid = eidx < E;
  const int ee = valid ? eidx : (E - 1);

  const int sn = src[ee];
  const int dn = dst[ee];
  const float* ar = xWni + (size_t)sn * DOS;
  const float* br = xWnj + (size_t)dn * DOS;

  float acc[DO];
  constexpr int J4 = DO & ~3;
  #pragma unroll
  for (int j = 0; j < J4; j += 4) {
    float4 a4 = *(const float4*)(ar + j);
    float4 b4 = *(const float4*)(br + j);
    acc[j+0] = bias[j+0] + a4.x + b4.x;
    acc[j+1] = bias[j+1] + a4.y + b4.y;
    acc[j+2] = bias[j+2] + a4.z + b4.z;
    acc[j+3] = bias[j+3] + a4.w + b4.w;
  }
  #pragma unroll
  for (int j = J4; j < DO; j++)
    acc[j] = bias[j] + ar[j] + br[j];

  const float* er = efeat + (size_t)ee * DIS;
  constexpr int K4 = DI & ~3;
  for (int k = 0; k < K4; k += 4) {
    float4 ev = *(const float4*)(er + k);
    float ea[4] = {ev.x, ev.y, ev.z, ev.w};
    #pragma unroll
    for (int kk = 0; kk < 4; kk++) {
      const float* wr = Wf + (size_t)(k + kk) * DO;
      #pragma unroll
      for (int j = 0; j < DO; j++)
        acc[j] = fmaf(ea[kk], wr[j], acc[j]);
    }
  }
  #pragma unroll
  for (int k = K4; k < DI; k++) {
    float ev = er[k];
    const float* wr = Wf + (size_t)k * DO;
    #pragma unroll
    for (int j = 0; j < DO; j++)
      acc[j] = fmaf(ev, wr[j], acc[j]);
  }

  float sc = 0.f;
  #pragma unroll
  for (int j = 0; j < DO; j++) {
    float v = acc[j];
    v = (v > 0.f) ? v : 0.01f * v;
    acc[j] = v;
    if (SCORE) sc += v * attn[j];
  }

  if (valid) {
    float* orow = fout + (size_t)eidx * DOS;
    #pragma unroll
    for (int j = 0; j < J4; j += 4)
      *(float4*)(orow + j) = make_float4(acc[j], acc[j+1], acc[j+2], acc[j+3]);
    #pragma unroll
    for (int j = J4; j < DO; j++) orow[j] = acc[j];
    if constexpr (SCORE) {
      score[eidx] = sc;
      atomicMax(&menc[dn], enc_f(sc));
    }
  }
}

__global__ __launch_bounds__(NTH) void softmax_ex_k(float* __restrict__ score,
    const int* __restrict__ dst, const unsigned* __restrict__ menc,
    float* __restrict__ ssum, int E)
{
  int i = blockIdx.x * NTH + threadIdx.x;
  if (i < E) {
    int d = dst[i];
    float ex = expf(score[i] - dec_f(menc[d]));
    score[i] = ex;
    atomicAdd(&ssum[d], ex);
  }
}

__global__ __launch_bounds__(NTH) void softmax_norm_k(float* __restrict__ score,
    const float* __restrict__ ssum, const int* __restrict__ dst, int E)
{
  int i = blockIdx.x * NTH + threadIdx.x;
  if (i < E) score[i] = score[i] / ssum[dst[i]];
}

template<int DO, int HS, int OS>
__global__ __launch_bounds__(NTH) void scatter_h_k(const float* __restrict__ a,
    const int* __restrict__ src, const int* __restrict__ dst,
    const float* __restrict__ h, float* __restrict__ hout, int E)
{
  long long idx = (long long)blockIdx.x * NTH + threadIdx.x;
  if (idx < (long long)E * DO) {
    int e = (int)(idx / DO);
    int col = (int)(idx - (long long)e * DO);
    atomicAdd(&hout[(size_t)dst[e] * OS + col], h[(size_t)src[e] * HS + col] * a[e]);
  }
}

// float4 variant: one thread handles 4 columns (1 vector gather + 4 atomics)
template<int DO4, int HS, int OS>
__global__ __launch_bounds__(NTH) void scatter_h4_k(const float* __restrict__ a,
    const int* __restrict__ src, const int* __restrict__ dst,
    const float* __restrict__ h, float* __restrict__ hout, int E)
{
  long long idx = (long long)blockIdx.x * NTH + threadIdx.x;
  if (idx < (long long)E * DO4) {
    int e = (int)(idx / DO4);
    int c = (int)(idx - (long long)e * DO4);
    float av = a[e];
    float4 hv = *(const float4*)(h + (size_t)src[e] * HS + c * 4);
    float* op = hout + (size_t)dst[e] * OS + c * 4;
    atomicAdd(op + 0, hv.x * av);
    atomicAdd(op + 1, hv.y * av);
    atomicAdd(op + 2, hv.z * av);
    atomicAdd(op + 3, hv.w * av);
  }
}

extern "C" void kernel_launch(void* const* d_in, const int* in_sizes, int n_in,
                              void* d_out, int out_size, void* d_ws, size_t ws_size,
                              hipStream_t stream)
{
  const float* x    = (const float*)d_in[0];
  const float* e    = (const float*)d_in[1];
  const int*   src  = (const int*)d_in[2];
  const int*   dst  = (const int*)d_in[3];
  const float* W_n1 = (const float*)d_in[4];   const float* b_n1  = (const float*)d_in[5];
  const float* W_ni1= (const float*)d_in[6];   const float* W_nj1 = (const float*)d_in[7];
  const float* W_f1 = (const float*)d_in[8];   const float* attn1 = (const float*)d_in[9];
  const float* bias1= (const float*)d_in[10];
  const float* W_n2 = (const float*)d_in[11];  const float* b_n2  = (const float*)d_in[12];
  const float* W_ni2= (const float*)d_in[13];  const float* W_nj2 = (const float*)d_in[14];
  const float* W_f2 = (const float*)d_in[15];  const float* attn2 = (const float*)d_in[16];
  const float* bias2= (const float*)d_in[17];
  const float* W_n3 = (const float*)d_in[18];  const float* b_n3  = (const float*)d_in[19];
  const float* W_ni3= (const float*)d_in[20];  const float* W_nj3 = (const float*)d_in[21];
  const float* W_f3 = (const float*)d_in[22];  const float* attn3 = (const float*)d_in[23];
  const float* bias3= (const float*)d_in[24];
  (void)W_n3; (void)b_n3;  // layer-3 node aggregation is dead (only f3 returned)

  const int N = in_sizes[0] / 128;
  const int E = in_sizes[2];

  float* ws = (float*)d_ws;
  size_t off = 0;
  float* fbuf1 = ws + off; off += (size_t)E * 128;   // f1 [E,128]
  float* fbuf2 = ws + off; off += (size_t)E * 32;    // f2 [E,30] padded to 32
  float* xWni  = ws + off; off += (size_t)N * 128;
  float* xWnj  = ws + off; off += (size_t)N * 128;
  float* hbuf  = ws + off; off += (size_t)N * 128;
  float* nodeA = ws + off; off += (size_t)N * 128;   // h_out layer1 [N,128]
  float* nodeB = ws + off; off += (size_t)N * 32;    // h_out layer2 [N,30] pad 32
  float* scoreb= ws + off; off += (size_t)E;         // score -> ex -> a (in place)
  unsigned* menc = (unsigned*)(ws + off); off += (size_t)N;
  float* sbuf  = ws + off; off += (size_t)N;

  const int groupsN = (N + 63) / 64;
  const int groupsE = (E + 63) / 64;   // staged edge: 1 group per block
  const int gN2 = (groupsN + 1) / 2;   // node JSPLIT=2: 2 groups/block
  const int gN4 = (groupsN + 3) / 4;   // node JSPLIT=1: 4 groups/block
  const int gE4 = (groupsE + 3) / 4;   // layer-2 edge (direct, 4 waves/block)
  const int gEe = (E + NTH - 1) / NTH;

  // ---------------- layer 1: di=128 -> do=128 (staged, 4 subs, acc[32]) ----------------
  node_linear_k<128,128,128,128,2,4><<<gN2,NTH,0,stream>>>(x, W_ni1, nullptr, xWni, N);
  node_linear_k<128,128,128,128,2,4><<<gN2,NTH,0,stream>>>(x, W_nj1, nullptr, xWnj, N);
  node_linear_k<128,128,128,128,2,4><<<gN2,NTH,0,stream>>>(x, W_n1,  b_n1,   hbuf, N);
  hipMemsetAsync(menc, 0, (size_t)N * 4, stream);   // enc(-inf)=0 lower bound
  hipMemsetAsync(sbuf, 0, (size_t)N * 4, stream);
  hipMemsetAsync(nodeA, 0, (size_t)N * 128 * 4, stream);
  edge_f_s_k<128,128,32,128,128,true,6><<<groupsE,NTH,0,stream>>>(e, xWni, xWnj, W_f1, attn1, bias1,
                                                                  src, dst, fbuf1, scoreb, menc, E);
  softmax_ex_k<<<gEe,NTH,0,stream>>>(scoreb, dst, menc, sbuf, E);
  softmax_norm_k<<<gEe,NTH,0,stream>>>(scoreb, sbuf, dst, E);
  scatter_h4_k<32,128,128><<<(int)(((long long)E*32 + NTH-1)/NTH),NTH,0,stream>>>(scoreb, src, dst, hbuf, nodeA, E);

  // ---------------- layer 2: di=128 -> do=30 (pad 32, direct JSPLIT=1) ----------------
  node_linear_k<128,128,30,32,1,5><<<gN4,NTH,0,stream>>>(nodeA, W_ni2, nullptr, xWni, N);
  node_linear_k<128,128,30,32,1,5><<<gN4,NTH,0,stream>>>(nodeA, W_nj2, nullptr, xWnj, N);
  node_linear_k<128,128,30,32,1,5><<<gN4,NTH,0,stream>>>(nodeA, W_n2,  b_n2,   hbuf, N);
  hipMemsetAsync(menc, 0, (size_t)N * 4, stream);
  hipMemsetAsync(sbuf, 0, (size_t)N * 4, stream);
  hipMemsetAsync(nodeB, 0, (size_t)N * 32 * 4, stream);
  edge_f_k<128,128,30,32,true,5><<<gE4,NTH,0,stream>>>(fbuf1, xWni, xWnj, W_f2, attn2, bias2,
                                                       src, dst, fbuf2, scoreb, menc, E);
  softmax_ex_k<<<gEe,NTH,0,stream>>>(scoreb, dst, menc, sbuf, E);
  softmax_norm_k<<<gEe,NTH,0,stream>>>(scoreb, sbuf, dst, E);
  scatter_h_k<30,32,32><<<(int)(((long long)E*30 + NTH-1)/NTH),NTH,0,stream>>>(scoreb, src, dst, hbuf, nodeB, E);

  // ---------------- layer 3: di=30 (stride 32) -> do=64 — only f3 (staged, acc[16]) ----------------
  node_linear_k<30,32,64,64,2,4><<<gN2,NTH,0,stream>>>(nodeB, W_ni3, nullptr, xWni, N);
  node_linear_k<30,32,64,64,2,4><<<gN2,NTH,0,stream>>>(nodeB, W_nj3, nullptr, xWnj, N);
  edge_f_s_k<30,32,16,64,64,false,7><<<groupsE,NTH,0,stream>>>(fbuf2, xWni, xWnj, W_f3, attn3, bias3,
                                                               src, dst, (float*)d_out, nullptr, nullptr, E);
}